// Round 3
// baseline (295.273 us; speedup 1.0000x reference)
//
#include <hip/hip_runtime.h>

#define N_TOK 65536
#define DIN   256
#define DOUT  256
#define NEXP  8
#define NPAIR 28   // C(8,2)

typedef __bf16 bf16x8 __attribute__((ext_vector_type(8)));
typedef __bf16 bf16x4 __attribute__((ext_vector_type(4)));
typedef float  f32x4  __attribute__((ext_vector_type(4)));

// global -> LDS async DMA, 16B per lane. LDS dst is wave-uniform base + lane*16.
__device__ __forceinline__ void cp16_g2l(const void* g, void* l) {
  auto gp = (const __attribute__((address_space(1))) unsigned int*)(unsigned long long)g;
  auto lp = (__attribute__((address_space(3))) unsigned int*)(unsigned long long)l;
  __builtin_amdgcn_global_load_lds(gp, lp, 16, 0, 0);
}

// ---------------------------------------------------------------------------
// prep: Wt[e][n][k] = bf16(We[e][k][n]) via LDS-tiled 32x32 transpose.
// grid = 512 (8 experts x 64 tiles), block = 256. Also zeros cnt[28].
// ---------------------------------------------------------------------------
__global__ __launch_bounds__(256) void prep_kernel(const float* __restrict__ We,
                                                   __bf16* __restrict__ Wt,
                                                   int* __restrict__ cnt) {
  __shared__ float T[32 * 33];
  int bid = blockIdx.x;
  if (bid == 0 && threadIdx.x < NPAIR) cnt[threadIdx.x] = 0;
  int e = bid >> 6;          // 8 experts
  int t = bid & 63;          // 64 tiles: 8 k-tiles x 8 n-tiles
  int k0 = (t >> 3) * 32, n0 = (t & 7) * 32;
  int tid = threadIdx.x;
  int cc = tid & 31;         // coalesced dim
  int rr = tid >> 5;         // 0..7
#pragma unroll
  for (int i = 0; i < 4; i++) {
    int k = i * 8 + rr;
    T[cc * 33 + k] = We[(size_t)(e * 256 + k0 + k) * 256 + n0 + cc];
  }
  __syncthreads();
#pragma unroll
  for (int i = 0; i < 4; i++) {
    int n = i * 8 + rr;
    Wt[(size_t)(e * 256 + n0 + n) * 256 + k0 + cc] = (__bf16)T[n * 33 + cc];
  }
}

// ---------------------------------------------------------------------------
// router v2: 4 lanes per token. Lane (token, q) reads float4 chunks c=j*4+q
// (per-instruction: 16 tokens x 4 contiguous lanes = 16 full 64B lines).
// Logits reduced across the quad via shfl_xor. fp32 with fp64 recompute when
// the 2nd/3rd gap < 5e-3 (selection must match numpy). Emits xb = bf16(x).
// grid = 1024 blocks x 256 thr (64 tokens/block).
// ---------------------------------------------------------------------------
__global__ __launch_bounds__(256) void router_kernel(const float* __restrict__ x,
                                                     const float* __restrict__ Wr,
                                                     __bf16* __restrict__ xb,
                                                     int* __restrict__ cnt,
                                                     unsigned short* __restrict__ pidx,
                                                     float* __restrict__ pw) {
  __shared__ float WrT[NEXP * DIN];   // [e][dim]
  __shared__ int lcnt[NPAIR];
  __shared__ int gbase[NPAIR];
  int tid = threadIdx.x;
  for (int i = tid; i < NEXP * DIN; i += 256) {
    int e = i >> 8, d = i & 255;
    WrT[i] = Wr[d * NEXP + e];
  }
  if (tid < NPAIR) lcnt[tid] = 0;
  __syncthreads();

  int token = blockIdx.x * 64 + (tid >> 2);
  int q = tid & 3;
  const float* xrow = x + (size_t)token * DIN;
  const float4* xr4 = (const float4*)xrow;
  __bf16* xbrow = xb + (size_t)token * DIN;

  float acc[NEXP];
#pragma unroll
  for (int e = 0; e < NEXP; e++) acc[e] = 0.f;

#pragma unroll 4
  for (int j = 0; j < 16; j++) {
    int c = j * 4 + q;
    float4 v = xr4[c];
    bf16x4 bv;
    bv[0] = (__bf16)v.x; bv[1] = (__bf16)v.y; bv[2] = (__bf16)v.z; bv[3] = (__bf16)v.w;
    *(bf16x4*)(xbrow + c * 4) = bv;
#pragma unroll
    for (int e = 0; e < NEXP; e++) {
      float4 w = *(const float4*)&WrT[e * DIN + c * 4];
      acc[e] += v.x * w.x + v.y * w.y + v.z * w.z + v.w * w.w;
    }
  }
  // quad reduction (lanes q, q^1, q^2)
#pragma unroll
  for (int e = 0; e < NEXP; e++) {
    acc[e] += __shfl_xor(acc[e], 1);
    acc[e] += __shfl_xor(acc[e], 2);
  }

  int p = -1, lpos = 0, a = 0, b2 = 0;
  float wa = 0.f;
  if (q == 0) {
    int best = 0;
#pragma unroll
    for (int e = 1; e < NEXP; e++) if (acc[e] > acc[best]) best = e;
    int sec = (best == 0) ? 1 : 0;
#pragma unroll
    for (int e = 0; e < NEXP; e++)
      if (e != best && e != sec && acc[e] > acc[sec]) sec = e;
    float l3 = -1e30f;
#pragma unroll
    for (int e = 0; e < NEXP; e++)
      if (e != best && e != sec) l3 = fmaxf(l3, acc[e]);

    float diff = acc[sec] - acc[best];
    if (acc[sec] - l3 < 5e-3f) {       // near-tie on the 2/3 boundary -> fp64
      double d[NEXP];
#pragma unroll
      for (int e = 0; e < NEXP; e++) d[e] = 0.0;
      for (int c = 0; c < 64; c++) {
        float4 v = xr4[c];
#pragma unroll
        for (int e = 0; e < NEXP; e++) {
          const float* w = &WrT[e * DIN + c * 4];
          d[e] += (double)v.x * w[0] + (double)v.y * w[1] +
                  (double)v.z * w[2] + (double)v.w * w[3];
        }
      }
      best = 0;
#pragma unroll
      for (int e = 1; e < NEXP; e++) if (d[e] > d[best]) best = e;
      sec = (best == 0) ? 1 : 0;
#pragma unroll
      for (int e = 0; e < NEXP; e++)
        if (e != best && e != sec && d[e] > d[sec]) sec = e;
      diff = (float)(d[sec] - d[best]);
    }

    float wb = 1.f / (1.f + expf(diff));  // weight of `best`
    if (best < sec) { a = best; b2 = sec; wa = wb; }
    else            { a = sec;  b2 = best; wa = 1.f - wb; }
    p = a * (15 - a) / 2 + (b2 - a - 1);
    lpos = atomicAdd(&lcnt[p], 1);
  }
  __syncthreads();
  if (tid < NPAIR) gbase[tid] = atomicAdd(&cnt[tid], lcnt[tid]);
  __syncthreads();
  if (q == 0) {
    int pos = gbase[p] + lpos;
    pidx[p * N_TOK + pos] = (unsigned short)token;
    pw[p * N_TOK + pos] = wa;
  }
}

// ---------------------------------------------------------------------------
// grouped GEMM v3: stage A ONCE (128 tokens x full K=256, 64KB LDS, async DMA
// with XOR-seg swizzle), then loop 4 column strips of 64 reusing staged A.
// Dual accumulators (expert a, expert b) per strip; B read direct from global
// (Wt L1/L2-hot, fully-coalesced 64B-line reads). out written exactly once.
// grid = 540 blocks x 256 thr, 2 blocks/CU (LDS-capped).
// ---------------------------------------------------------------------------
__global__ __launch_bounds__(256, 2) void moe_gemm_kernel(const __bf16* __restrict__ xb,
                                                          const __bf16* __restrict__ Wt,
                                                          const float* __restrict__ be,
                                                          const int* __restrict__ cnt,
                                                          const unsigned short* __restrict__ pidx,
                                                          const float* __restrict__ pw,
                                                          float* __restrict__ out) {
  // As: row r (0..127) x 32 segs of 16B; global seg s stored at slot s^(r&7).
  __shared__ __bf16 As[128 * 256];
  __shared__ unsigned short tokL[128];
  __shared__ float wL[128];
  __shared__ int cntL[NPAIR];
  __shared__ int meta[3];

  int tid = threadIdx.x;
  int tile = blockIdx.x;

  if (tid < NPAIR) cntL[tid] = cnt[tid];
  __syncthreads();
  if (tid == 0) {
    int s = 0, pp = -1, lt = 0, c = 0;
    for (int qq = 0; qq < NPAIR; qq++) {
      int cq = cntL[qq];
      int tq = (cq + 127) >> 7;
      if (tile < s + tq) { pp = qq; lt = tile - s; c = cq; break; }
      s += tq;
    }
    meta[0] = pp; meta[1] = lt; meta[2] = c;
  }
  __syncthreads();
  int p = meta[0];
  if (p < 0) return;
  int lt = meta[1], cnt_p = meta[2];

  int a = 0, rem = p;
  while (rem >= 7 - a) { rem -= 7 - a; a++; }
  int b2 = a + 1 + rem;
  int r0 = lt * 128;

  if (tid < 128) {
    int gr = r0 + tid;
    tokL[tid] = (gr < cnt_p) ? pidx[p * N_TOK + gr] : (unsigned short)0;
    wL[tid]   = (gr < cnt_p) ? pw[p * N_TOK + gr] : 0.f;
  }
  __syncthreads();

  // ---- stage A (one burst): 4096 segs of 16B, 16 per thread
#pragma unroll
  for (int i = 0; i < 16; i++) {
    int g = tid + 256 * i;          // slot index
    int r = g >> 5, sl = g & 31;
    int s = sl ^ (r & 7);
    cp16_g2l(xb + (size_t)tokL[r] * DIN + s * 8, &As[g * 8]);
  }
  __builtin_amdgcn_s_waitcnt(0x0F70);   // vmcnt(0)
  __syncthreads();

  const int lane = tid & 63, wid = tid >> 6;
  const int wm = wid & 1, wn = wid >> 1;
  const int c16 = lane & 15, quad = lane >> 4;

  const __bf16* WtA = Wt + (size_t)a  * DOUT * DIN;
  const __bf16* WtB = Wt + (size_t)b2 * DOUT * DIN;

  for (int nh = 0; nh < 4; nh++) {
    f32x4 accA[4][2], accB[4][2];
#pragma unroll
    for (int mi = 0; mi < 4; mi++)
#pragma unroll
      for (int ni = 0; ni < 2; ni++)
#pragma unroll
        for (int r = 0; r < 4; r++) { accA[mi][ni][r] = 0.f; accB[mi][ni][r] = 0.f; }

#pragma unroll
    for (int kstep = 0; kstep < 8; kstep++) {
      bf16x8 af[4], ba[2], bb[2];
      int o = kstep * 4 + quad;
#pragma unroll
      for (int mi = 0; mi < 4; mi++) {
        int row = wm * 64 + mi * 16 + c16;
        af[mi] = *(const bf16x8*)&As[row * 256 + (o ^ (row & 7)) * 8];
      }
      int koff = kstep * 32 + quad * 8;
#pragma unroll
      for (int ni = 0; ni < 2; ni++) {
        int col = nh * 64 + wn * 32 + ni * 16 + c16;
        ba[ni] = *(const bf16x8*)&WtA[(size_t)col * DIN + koff];
        bb[ni] = *(const bf16x8*)&WtB[(size_t)col * DIN + koff];
      }
#pragma unroll
      for (int mi = 0; mi < 4; mi++)
#pragma unroll
        for (int ni = 0; ni < 2; ni++) {
          accA[mi][ni] = __builtin_amdgcn_mfma_f32_16x16x32_bf16(af[mi], ba[ni], accA[mi][ni], 0, 0, 0);
          accB[mi][ni] = __builtin_amdgcn_mfma_f32_16x16x32_bf16(af[mi], bb[ni], accB[mi][ni], 0, 0, 0);
        }
    }

    // epilogue for this strip
#pragma unroll
    for (int ni = 0; ni < 2; ni++) {
      int gcol = nh * 64 + wn * 32 + ni * 16 + c16;
      float bea = be[a * DOUT + gcol];
      float beb = be[b2 * DOUT + gcol];
#pragma unroll
      for (int mi = 0; mi < 4; mi++) {
#pragma unroll
        for (int r = 0; r < 4; r++) {
          int row = wm * 64 + mi * 16 + quad * 4 + r;
          if (r0 + row < cnt_p) {
            float w = wL[row];
            out[(size_t)tokL[row] * DOUT + gcol] =
                w * (accA[mi][ni][r] + bea) + (1.f - w) * (accB[mi][ni][r] + beb);
          }
        }
      }
    }
  }
}

// ---------------------------------------------------------------------------
extern "C" void kernel_launch(void* const* d_in, const int* in_sizes, int n_in,
                              void* d_out, int out_size, void* d_ws, size_t ws_size,
                              hipStream_t stream) {
  const float* x  = (const float*)d_in[0];
  const float* Wr = (const float*)d_in[1];
  const float* We = (const float*)d_in[2];
  const float* be = (const float*)d_in[3];
  float* out = (float*)d_out;

  // ws layout (~44.1 MB):
  //   [0, 1MB)        : Wt  bf16 [8][256][256]  ([e][n][k])
  //   [1MB, 33MB)     : xb  bf16 [65536][256]
  //   [33MB, +512B)   : cnt[28]
  //   [+, +3.5MB)     : pidx ushort [28][65536]
  //   [+, +7MB)       : pw   float  [28][65536]
  char* w = (char*)d_ws;
  __bf16* Wt = (__bf16*)w;
  __bf16* xb = (__bf16*)(w + (1u << 20));
  int* cnt = (int*)(w + (33u << 20));
  unsigned short* pidx = (unsigned short*)(w + (33u << 20) + 512);
  float* pw = (float*)(w + (33u << 20) + 512 + (size_t)NPAIR * N_TOK * 2);

  prep_kernel<<<512, 256, 0, stream>>>(We, Wt, cnt);
  router_kernel<<<N_TOK / 64, 256, 0, stream>>>(x, Wr, xb, cnt, pidx, pw);
  // max tiles = sum_p ceil(cnt_p/128) <= 512 + 27 = 539
  moe_gemm_kernel<<<540, 256, 0, stream>>>(xb, Wt, be, cnt, pidx, pw, out);
}

// Round 4
// 281.744 us; speedup vs baseline: 1.0480x; 1.0480x over previous
//
#include <hip/hip_runtime.h>

#define N_TOK 65536
#define DIN   256
#define DOUT  256
#define NEXP  8
#define NPAIR 28   // C(8,2)

typedef __bf16 bf16x8 __attribute__((ext_vector_type(8)));
typedef __bf16 bf16x4 __attribute__((ext_vector_type(4)));
typedef float  f32x4  __attribute__((ext_vector_type(4)));

// global -> LDS async DMA, 16B per lane. LDS dst is wave-uniform base + lane*16.
__device__ __forceinline__ void cp16_g2l(const void* g, void* l) {
  auto gp = (const __attribute__((address_space(1))) unsigned int*)(unsigned long long)g;
  auto lp = (__attribute__((address_space(3))) unsigned int*)(unsigned long long)l;
  __builtin_amdgcn_global_load_lds(gp, lp, 16, 0, 0);
}

// ---------------------------------------------------------------------------
// prep: Wt[e][n][k] = bf16(We[e][k][n]) via LDS-tiled 32x32 transpose.
// grid = 512 (8 experts x 64 tiles), block = 256. Also zeros cnt[28].
// ---------------------------------------------------------------------------
__global__ __launch_bounds__(256) void prep_kernel(const float* __restrict__ We,
                                                   __bf16* __restrict__ Wt,
                                                   int* __restrict__ cnt) {
  __shared__ float T[32 * 33];
  int bid = blockIdx.x;
  if (bid == 0 && threadIdx.x < NPAIR) cnt[threadIdx.x] = 0;
  int e = bid >> 6;
  int t = bid & 63;
  int k0 = (t >> 3) * 32, n0 = (t & 7) * 32;
  int tid = threadIdx.x;
  int cc = tid & 31;
  int rr = tid >> 5;
#pragma unroll
  for (int i = 0; i < 4; i++) {
    int k = i * 8 + rr;
    T[cc * 33 + k] = We[(size_t)(e * 256 + k0 + k) * 256 + n0 + cc];
  }
  __syncthreads();
#pragma unroll
  for (int i = 0; i < 4; i++) {
    int n = i * 8 + rr;
    Wt[(size_t)(e * 256 + n0 + n) * 256 + k0 + cc] = (__bf16)T[n * 33 + cc];
  }
}

// ---------------------------------------------------------------------------
// router v3: 8 lanes per token (32 tokens/block, grid 2048 -> 32 waves/CU).
// Lane (token,q) handles float4 chunks c=j*8+q: per token per j, 8 lanes cover
// 128B contiguous read and 64B contiguous xb write (full lines both ways).
// Butterfly shfl gives ALL lanes the logit sums; fp64 recompute (cooperative
// across the token's 8 lanes) when the 2nd/3rd gap < 5e-3.
// ---------------------------------------------------------------------------
__global__ __launch_bounds__(256, 8) void router_kernel(const float* __restrict__ x,
                                                        const float* __restrict__ Wr,
                                                        __bf16* __restrict__ xb,
                                                        int* __restrict__ cnt,
                                                        unsigned short* __restrict__ pidx,
                                                        float* __restrict__ pw) {
  __shared__ float WrT[NEXP * DIN];   // [e][dim]
  __shared__ int lcnt[NPAIR];
  __shared__ int gbase[NPAIR];
  int tid = threadIdx.x;
  for (int i = tid; i < NEXP * DIN; i += 256) {
    int e = i >> 8, d = i & 255;
    WrT[i] = Wr[d * NEXP + e];
  }
  if (tid < NPAIR) lcnt[tid] = 0;
  __syncthreads();

  int token = blockIdx.x * 32 + (tid >> 3);
  int q = tid & 7;
  const float4* xr4 = (const float4*)(x + (size_t)token * DIN);
  __bf16* xbrow = xb + (size_t)token * DIN;

  float acc[NEXP];
#pragma unroll
  for (int e = 0; e < NEXP; e++) acc[e] = 0.f;

#pragma unroll
  for (int j = 0; j < 8; j++) {
    int c = j * 8 + q;
    float4 v = xr4[c];
    bf16x4 bv;
    bv[0] = (__bf16)v.x; bv[1] = (__bf16)v.y; bv[2] = (__bf16)v.z; bv[3] = (__bf16)v.w;
    *(bf16x4*)(xbrow + c * 4) = bv;
#pragma unroll
    for (int e = 0; e < NEXP; e++) {
      float4 w = *(const float4*)&WrT[e * DIN + c * 4];  // broadcast, conflict-free
      acc[e] += v.x * w.x + v.y * w.y + v.z * w.z + v.w * w.w;
    }
  }
  // butterfly: every lane of the token gets the full sums
#pragma unroll
  for (int e = 0; e < NEXP; e++) {
    acc[e] += __shfl_xor(acc[e], 1);
    acc[e] += __shfl_xor(acc[e], 2);
    acc[e] += __shfl_xor(acc[e], 4);
  }

  int best = 0;
#pragma unroll
  for (int e = 1; e < NEXP; e++) if (acc[e] > acc[best]) best = e;
  int sec = (best == 0) ? 1 : 0;
#pragma unroll
  for (int e = 0; e < NEXP; e++)
    if (e != best && e != sec && acc[e] > acc[sec]) sec = e;
  float l3 = -1e30f;
#pragma unroll
  for (int e = 0; e < NEXP; e++)
    if (e != best && e != sec) l3 = fmaxf(l3, acc[e]);

  float diff = acc[sec] - acc[best];
  bool need = (acc[sec] - l3) < 5e-3f;   // 2/3 boundary near-tie -> fp64 redo
  if (need) {                             // cooperative across the 8 lanes
    double d[NEXP];
#pragma unroll
    for (int e = 0; e < NEXP; e++) d[e] = 0.0;
    for (int j = 0; j < 8; j++) {
      int c = j * 8 + q;
      float4 v = xr4[c];                  // L1/L2-hot reload
#pragma unroll
      for (int e = 0; e < NEXP; e++) {
        const float* w = &WrT[e * DIN + c * 4];
        d[e] += (double)v.x * w[0] + (double)v.y * w[1] +
                (double)v.z * w[2] + (double)v.w * w[3];
      }
    }
#pragma unroll
    for (int e = 0; e < NEXP; e++) {
      d[e] += __shfl_xor(d[e], 1);
      d[e] += __shfl_xor(d[e], 2);
      d[e] += __shfl_xor(d[e], 4);
    }
    best = 0;
#pragma unroll
    for (int e = 1; e < NEXP; e++) if (d[e] > d[best]) best = e;
    sec = (best == 0) ? 1 : 0;
#pragma unroll
    for (int e = 0; e < NEXP; e++)
      if (e != best && e != sec && d[e] > d[sec]) sec = e;
    diff = (float)(d[sec] - d[best]);
  }

  float wb = 1.f / (1.f + expf(diff));   // renormalized weight of `best`
  int a, b2; float wa;
  if (best < sec) { a = best; b2 = sec; wa = wb; }
  else            { a = sec;  b2 = best; wa = 1.f - wb; }
  int p = a * (15 - a) / 2 + (b2 - a - 1);

  int lpos = 0;
  if (q == 0) lpos = atomicAdd(&lcnt[p], 1);
  __syncthreads();
  if (tid < NPAIR) gbase[tid] = atomicAdd(&cnt[tid], lcnt[tid]);
  __syncthreads();
  if (q == 0) {
    int pos = gbase[p] + lpos;
    pidx[p * N_TOK + pos] = (unsigned short)token;
    pw[p * N_TOK + pos] = wa;
  }
}

// ---------------------------------------------------------------------------
// grouped GEMM v4: 64-token x 128-col tiles (nh = col half), full K=256
// staged once (32KB LDS, async DMA, XOR-seg swizzle -> conflict-free b128).
// 4 blocks/CU (launch_bounds(256,4)), grid ~2104 = ~2 residency rounds.
// Dual accumulators (expert a,b); B direct from global (Wt 1MB, L2-hot).
// out written exactly once.
// ---------------------------------------------------------------------------
__global__ __launch_bounds__(256, 4) void moe_gemm_kernel(const __bf16* __restrict__ xb,
                                                          const __bf16* __restrict__ Wt,
                                                          const float* __restrict__ be,
                                                          const int* __restrict__ cnt,
                                                          const unsigned short* __restrict__ pidx,
                                                          const float* __restrict__ pw,
                                                          float* __restrict__ out) {
  // As: row r (0..63) x 32 segs of 16B; global seg s stored at slot s^(r&7).
  __shared__ __bf16 As[64 * 256];
  __shared__ unsigned short tokL[64];
  __shared__ float wL[64];
  __shared__ int cntL[NPAIR];
  __shared__ int meta[3];

  int tid = threadIdx.x;
  int tile = blockIdx.x >> 1;
  int nh = blockIdx.x & 1;

  if (tid < NPAIR) cntL[tid] = cnt[tid];
  __syncthreads();
  if (tid == 0) {
    int s = 0, pp = -1, lt = 0, c = 0;
    for (int qq = 0; qq < NPAIR; qq++) {
      int cq = cntL[qq];
      int tq = (cq + 63) >> 6;
      if (tile < s + tq) { pp = qq; lt = tile - s; c = cq; break; }
      s += tq;
    }
    meta[0] = pp; meta[1] = lt; meta[2] = c;
  }
  __syncthreads();
  int p = meta[0];
  if (p < 0) return;
  int lt = meta[1], cnt_p = meta[2];

  int a = 0, rem = p;
  while (rem >= 7 - a) { rem -= 7 - a; a++; }
  int b2 = a + 1 + rem;
  int r0 = lt * 64;

  if (tid < 64) {
    int gr = r0 + tid;
    tokL[tid] = (gr < cnt_p) ? pidx[p * N_TOK + gr] : (unsigned short)0;
    wL[tid]   = (gr < cnt_p) ? pw[p * N_TOK + gr] : 0.f;
  }
  __syncthreads();

  // ---- stage A once: 2048 segs of 16B, 8 per thread
#pragma unroll
  for (int i = 0; i < 8; i++) {
    int g = tid + 256 * i;          // slot index
    int r = g >> 5, sl = g & 31;
    int s = sl ^ (r & 7);
    cp16_g2l(xb + (size_t)tokL[r] * DIN + s * 8, &As[g * 8]);
  }
  __builtin_amdgcn_s_waitcnt(0x0F70);   // vmcnt(0)
  __syncthreads();

  const int lane = tid & 63, wid = tid >> 6;
  const int wm = wid & 1, wn = wid >> 1;     // wave tile: 32 tok x 64 col
  const int c16 = lane & 15, quad = lane >> 4;

  const __bf16* WtA = Wt + (size_t)a  * DOUT * DIN;
  const __bf16* WtB = Wt + (size_t)b2 * DOUT * DIN;

  f32x4 accA[2][4], accB[2][4];
#pragma unroll
  for (int mi = 0; mi < 2; mi++)
#pragma unroll
    for (int ni = 0; ni < 4; ni++)
#pragma unroll
      for (int r = 0; r < 4; r++) { accA[mi][ni][r] = 0.f; accB[mi][ni][r] = 0.f; }

#pragma unroll 2
  for (int kstep = 0; kstep < 8; kstep++) {
    bf16x8 af[2], ba[4], bb[4];
    int koff = kstep * 32 + quad * 8;
    int seg = kstep * 4 + quad;
#pragma unroll
    for (int ni = 0; ni < 4; ni++) {
      int col = nh * 128 + wn * 64 + ni * 16 + c16;
      ba[ni] = *(const bf16x8*)&WtA[(size_t)col * DIN + koff];
      bb[ni] = *(const bf16x8*)&WtB[(size_t)col * DIN + koff];
    }
#pragma unroll
    for (int mi = 0; mi < 2; mi++) {
      int row = wm * 32 + mi * 16 + c16;
      af[mi] = *(const bf16x8*)&As[row * 256 + (seg ^ (row & 7)) * 8];
    }
#pragma unroll
    for (int mi = 0; mi < 2; mi++)
#pragma unroll
      for (int ni = 0; ni < 4; ni++) {
        accA[mi][ni] = __builtin_amdgcn_mfma_f32_16x16x32_bf16(af[mi], ba[ni], accA[mi][ni], 0, 0, 0);
        accB[mi][ni] = __builtin_amdgcn_mfma_f32_16x16x32_bf16(af[mi], bb[ni], accB[mi][ni], 0, 0, 0);
      }
  }

  // epilogue: weights + biases in fp32, store exactly once
#pragma unroll
  for (int ni = 0; ni < 4; ni++) {
    int gcol = nh * 128 + wn * 64 + ni * 16 + c16;
    float bea = be[a * DOUT + gcol];
    float beb = be[b2 * DOUT + gcol];
#pragma unroll
    for (int mi = 0; mi < 2; mi++) {
#pragma unroll
      for (int r = 0; r < 4; r++) {
        int row = wm * 32 + mi * 16 + quad * 4 + r;
        if (r0 + row < cnt_p) {
          float w = wL[row];
          out[(size_t)tokL[row] * DOUT + gcol] =
              w * (accA[mi][ni][r] + bea) + (1.f - w) * (accB[mi][ni][r] + beb);
        }
      }
    }
  }
}

// ---------------------------------------------------------------------------
extern "C" void kernel_launch(void* const* d_in, const int* in_sizes, int n_in,
                              void* d_out, int out_size, void* d_ws, size_t ws_size,
                              hipStream_t stream) {
  const float* x  = (const float*)d_in[0];
  const float* Wr = (const float*)d_in[1];
  const float* We = (const float*)d_in[2];
  const float* be = (const float*)d_in[3];
  float* out = (float*)d_out;

  // ws layout (~44.1 MB):
  //   [0, 1MB)        : Wt  bf16 [8][256][256]  ([e][n][k])
  //   [1MB, 33MB)     : xb  bf16 [65536][256]
  //   [33MB, +512B)   : cnt[28]
  //   [+, +3.5MB)     : pidx ushort [28][65536]
  //   [+, +7MB)       : pw   float  [28][65536]
  char* w = (char*)d_ws;
  __bf16* Wt = (__bf16*)w;
  __bf16* xb = (__bf16*)(w + (1u << 20));
  int* cnt = (int*)(w + (33u << 20));
  unsigned short* pidx = (unsigned short*)(w + (33u << 20) + 512);
  float* pw = (float*)(w + (33u << 20) + 512 + (size_t)NPAIR * N_TOK * 2);

  prep_kernel<<<512, 256, 0, stream>>>(We, Wt, cnt);
  router_kernel<<<N_TOK / 32, 256, 0, stream>>>(x, Wr, xb, cnt, pidx, pw);
  // max tiles = sum_p ceil(cnt_p/64) <= 1024 + 27 = 1051; x2 column halves
  moe_gemm_kernel<<<2104, 256, 0, stream>>>(xb, Wt, be, cnt, pidx, pw, out);
}